// Round 16
// baseline (1713.737 us; speedup 1.0000x reference)
//
#include <hip/hip_runtime.h>
#include <stdint.h>

#define NLAYERS 6
#define DMODEL  512
#define NHEADS  8
#define HDIM    64
#define INNER   2048
#define SEQ     128
#define BATCH   256
#define NTOK    (BATCH*SEQ)

typedef __attribute__((ext_vector_type(4))) float f32x4;
typedef __attribute__((ext_vector_type(8))) _Float16 hfrag;

typedef const __attribute__((address_space(1))) void* gas1p;
typedef __attribute__((address_space(3))) void* las3p;

__device__ __forceinline__ void load_lds16(const void* g, void* l) {
  __builtin_amdgcn_global_load_lds((gas1p)(uintptr_t)g, (las3p)(uint32_t)(uintptr_t)l, 16, 0, 0);
}

__device__ __forceinline__ ushort f2h(float f) {
  return __builtin_bit_cast(ushort, (_Float16)f);
}
__device__ __forceinline__ float h2f(ushort u) {
  return (float)__builtin_bit_cast(_Float16, u);
}

__device__ __forceinline__ f32x4 mfma16(hfrag a, hfrag b, f32x4 c) {
  return __builtin_amdgcn_mfma_f32_16x16x32_f16(a, b, c, 0, 0, 0);
}

// ---------------- weight prep (f32 -> f16, transposed to [N][K]) ----------------

__global__ void prep_qkv(const float* __restrict__ Wq, const float* __restrict__ Wk,
                         const float* __restrict__ Wv, const float* __restrict__ bq,
                         const float* __restrict__ bk, const float* __restrict__ bv,
                         ushort* __restrict__ Wt, float* __restrict__ biasq) {
  int idx = blockIdx.x*256 + threadIdx.x;
  if (idx >= NLAYERS*1536*512) return;
  const int k = idx & 511;
  const int n = (idx >> 9) % 1536;
  const int l = idx / (1536*512);
  const int which = n >> 9, hh = (n >> 6) & 7, e = n & 63;
  const float* W = (which == 0) ? Wq : ((which == 1) ? Wk : Wv);
  Wt[idx] = f2h(W[(((size_t)l*NHEADS + hh)*DMODEL + k)*HDIM + e]);
  if (k == 0) {
    const float* bb = (which == 0) ? bq : ((which == 1) ? bk : bv);
    biasq[l*1536 + n] = bb[((size_t)l*NHEADS + hh)*HDIM + e];
  }
}

__global__ void prep_w1(const float* __restrict__ W1, ushort* __restrict__ W1t) {
  int idx = blockIdx.x*256 + threadIdx.x;
  if (idx >= NLAYERS*INNER*512) return;
  const int k = idx & 511;
  const int n = (idx >> 9) % INNER;
  const int l = idx / (INNER*512);
  W1t[idx] = f2h(W1[((size_t)l*DMODEL + k)*INNER + n]);
}

__global__ void prep_w2(const float* __restrict__ W2, ushort* __restrict__ W2t) {
  int idx = blockIdx.x*256 + threadIdx.x;
  if (idx >= NLAYERS*512*INNER) return;
  const int k = idx & 2047;
  const int n = (idx >> 11) & 511;
  const int l = idx / (512*INNER);
  W2t[idx] = f2h(W2[((size_t)l*INNER + k)*DMODEL + n]);
}

// ---------------- embedding + positional encoding (f16 residual stream) ----------------

__global__ void embed_kernel(const int* __restrict__ x, const float* __restrict__ emb,
                             ushort* __restrict__ hb) {
  const int t = blockIdx.x;       // token 0..32767
  const int i = threadIdx.x;      // pair 0..255
  const int s = t & (SEQ-1);
  const int tok = x[t];
  const float freq = expf(-(float)i * (9.210340371976184f / 256.0f)); // 10000^(-i/256)
  const float th = (float)s * freq;
  const float sn = sinf(th), cs = cosf(th);
  const size_t base = (size_t)t*DMODEL;
  const float v0 = emb[(size_t)tok*DMODEL + 2*i]     + sn;
  const float v1 = emb[(size_t)tok*DMODEL + 2*i + 1] + cs;
  *(uint*)(hb + base + 2*i) = (uint)f2h(v0) | ((uint)f2h(v1) << 16);
}

// ---------------- 256x256 f16 MFMA GEMM, 8 waves, ring-2, 2 blocks/CU ----------
// C = A[M,K] @ Bt[N,K]^T. 8 waves (2M x 4N), wave tile 128x64, BK=32.
// 64 KB LDS (2 slots x 32 KB: A 16K + B 16K) -> 2 blocks/CU = 4 waves/SIMD:
// one block's vmcnt(0) drain + barrier hides under the other block's MFMA.
// Per K-tile: issue stage(kt+1 -> other slot) FIRST, then 12 ds_read_b128,
// 32 MFMA, vmcnt(0), one barrier. Ring-2 ledger: stage targets the slot whose
// tile (kt-1) was consumed before barrier(kt-1). LDS map: 64B rows, chunk
// pos = c ^ ((row>>1)&3), both sides (proven conflict-free).
// EPI: 0 = bias->f16, 1 = bias+relu->f16

template<int K, int EPI>
__global__ __launch_bounds__(512, 2) void gemm_2(
    const ushort* __restrict__ A, const ushort* __restrict__ Bt,
    const float* __restrict__ bias, ushort* __restrict__ outb,
    const int ldc, const int nbn) {
  __shared__ __align__(16) char lds[65536];
  constexpr int NKT = K / 32;
  const int t = threadIdx.x;
  const int lane = t & 63, w = t >> 6;
  const int wr = w >> 2, wc = w & 3;
  const int cpx = (int)gridDim.x >> 3;
  const int wg  = ((int)blockIdx.x & 7) * cpx + ((int)blockIdx.x >> 3);
  const int bm = wg / nbn, bn = wg % nbn;

  const int fr = lane & 15;
  const int cxor = (((lane >> 4) ^ ((fr >> 1) & 3)) << 4);

  float bias_r[4];
  #pragma unroll
  for (int n = 0; n < 4; ++n) bias_r[n] = bias[bn*256 + wc*64 + n*16 + fr];
  asm volatile("" : "+v"(bias_r[0]), "+v"(bias_r[1]), "+v"(bias_r[2]), "+v"(bias_r[3]));

  // staging: thread t -> row t>>2 (0..127; +128 on 2nd load), chunk (t&3)^((t>>3)&3)
  const int srow = t >> 2;
  const int scc  = (t & 3) ^ ((t >> 3) & 3);
  const ushort* aSrc = A  + ((size_t)bm*256 + srow)*K + scc*8;
  const ushort* bSrc = Bt + ((size_t)bn*256 + srow)*K + scc*8;

  auto stage = [&](int j, int slot) {      // 4 loads: A 16K + B 16K
    char* dst = lds + slot*32768 + t*16;
    load_lds16(aSrc + j*32,                 dst);
    load_lds16(aSrc + (size_t)128*K + j*32, dst + 8192);
    load_lds16(bSrc + j*32,                 dst + 16384);
    load_lds16(bSrc + (size_t)128*K + j*32, dst + 24576);
  };

  f32x4 acc[8][4] = {};

  stage(0, 0);
  asm volatile("s_waitcnt vmcnt(0)" ::: "memory");
  __builtin_amdgcn_s_barrier();

  #pragma unroll 1
  for (int kt = 0; kt < NKT; ++kt) {
    if (kt + 1 < NKT) stage(kt + 1, (kt + 1) & 1);   // issue early, other slot
    const char* sl = lds + (kt & 1)*32768;
    hfrag a[8], b[4];
    #pragma unroll
    for (int m = 0; m < 8; ++m)
      a[m] = *(const hfrag*)(sl + (wr*128 + m*16 + fr)*64 + cxor);
    #pragma unroll
    for (int n = 0; n < 4; ++n)
      b[n] = *(const hfrag*)(sl + 16384 + (wc*64 + n*16 + fr)*64 + cxor);
    __builtin_amdgcn_s_setprio(1);
    #pragma unroll
    for (int m = 0; m < 8; ++m)
      #pragma unroll
      for (int n = 0; n < 4; ++n)
        acc[m][n] = mfma16(a[m], b[n], acc[m][n]);
    __builtin_amdgcn_s_setprio(0);
    if (kt + 1 < NKT) {
      asm volatile("s_waitcnt vmcnt(0)" ::: "memory");  // tile kt+1 resident
      __builtin_amdgcn_s_barrier();
    }
  }

  // coalesced epilogue: 4 rounds x 64 rows (32 KB LDS), full-line stores.
  #pragma unroll
  for (int mm = 0; mm < 4; ++mm) {
    __syncthreads();
    #pragma unroll
    for (int mi = 0; mi < 2; ++mi) {
      const int m = mm*2 + mi;
      #pragma unroll
      for (int n = 0; n < 4; ++n) {
        const int cc16 = wc*4 + n;
        #pragma unroll
        for (int r4 = 0; r4 < 4; ++r4) {
          const int rr = ((lane >> 4) << 2) + r4;         // 0..15
          const int lr = wr*32 + mi*16 + rr;              // 0..63
          float v = acc[m][n][r4] + bias_r[n];
          if constexpr (EPI == 1) v = fmaxf(v, 0.0f);
          *(ushort*)(lds + lr*512 + ((cc16 ^ (rr >> 2)) << 5) + fr*2) = f2h(v);
        }
      }
    }
    __syncthreads();
    #pragma unroll
    for (int pr = 0; pr < 2; ++pr) {
      const int lr = (t >> 4) + pr*32;                    // 0..63
      const int grow = bm*256 + (lr >> 5)*128 + mm*32 + (lr & 31);
      ushort* gp = outb + (size_t)grow*ldc + bn*256;
      #pragma unroll
      for (int pc = 0; pc < 2; ++pc) {
        const int cj = (t & 15) + pc*16;
        const uint4 v = *(const uint4*)(lds + lr*512 + (((cj >> 1) ^ ((lr & 15) >> 2)) << 5) + ((cj & 1) << 4));
        *(uint4*)(gp + cj*8) = v;
      }
    }
  }
}

// ---------------- fused attention + residual-LN1 (r14 form) ----------------

__global__ __launch_bounds__(512, 1) void attn_ln(
    const ushort* __restrict__ qkv, ushort* __restrict__ hb) {
  __shared__ __align__(16) char lds[131072];
  __shared__ float red_[8], redq_[8], stat_[2];
  const int t = threadIdx.x;
  const int w = t >> 6, lane = t & 63;
  const int b = blockIdx.x, h = w;
  const int fr = lane & 15;
  const ushort* tokbase = qkv + (size_t)b*SEQ*1536;
  ushort* wl  = (ushort*)(lds + w*16384);
  ushort* kch = wl;
  ushort* vch = wl + 2048;

  f32x4 acc1[4][4] = {};
  #pragma unroll 1
  for (int sb = 0; sb < 4; ++sb) {
    const int s0 = sb*32;
    const int sr = lane >> 1;
    #pragma unroll
    for (int i = 0; i < 4; ++i) {
      const int cc  = i*2 + (lane & 1);
      const int ccs = cc ^ (sr & 7);
      const ushort* g = tokbase + (size_t)(s0+sr)*1536 + h*64 + cc*8;
      *(uint4*)(kch + sr*64 + ccs*8) = *(const uint4*)(g + 512);
      *(uint4*)(vch + sr*64 + ccs*8) = *(const uint4*)(g + 1024);
    }
    hfrag ak[4], av[4];
    #pragma unroll
    for (int m = 0; m < 4; ++m) {
      const int e1 = m*16 + (lane & 15);
      const int ccb = e1 >> 3, el = e1 & 7;
      #pragma unroll
      for (int j = 0; j < 8; ++j) {
        const int s = (lane >> 4)*8 + j;
        ak[m][j] = __builtin_bit_cast(_Float16, kch[s*64 + ((ccb ^ (s & 7))*8) + el]);
        av[m][j] = __builtin_bit_cast(_Float16, vch[s*64 + ((ccb ^ (s & 7))*8) + el]);
      }
    }
    #pragma unroll
    for (int m = 0; m < 4; ++m)
      #pragma unroll
      for (int n = 0; n < 4; ++n)
        acc1[m][n] = mfma16(ak[m], av[n], acc1[m][n]);
  }

  ushort* tv = wl;
  #pragma unroll
  for (int m = 0; m < 4; ++m)
    #pragma unroll
    for (int n = 0; n < 4; ++n)
      #pragma unroll
      for (int r4 = 0; r4 < 4; ++r4) {
        const int e1 = m*16 + (lane >> 4)*4 + r4;
        const int e2 = n*16 + (lane & 15);
        tv[e2*72 + e1] = f2h(acc1[m][n][r4] * 0.125f);
      }

  f32x4 acc2[8][4] = {};
  #pragma unroll
  for (int eb = 0; eb < 2; ++eb) {
    const int e1b = eb*32 + (lane >> 4)*8;
    hfrag aq[8], bk2[4];
    #pragma unroll
    for (int m = 0; m < 8; ++m) {
      const int s = m*16 + (lane & 15);
      aq[m] = *(const hfrag*)(tokbase + (size_t)s*1536 + h*64 + e1b);
    }
    #pragma unroll
    for (int n = 0; n < 4; ++n) {
      const int e2 = n*16 + (lane & 15);
      bk2[n] = *(const hfrag*)(tv + e2*72 + e1b);
    }
    #pragma unroll
    for (int m = 0; m < 8; ++m)
      #pragma unroll
      for (int n = 0; n < 4; ++n)
        acc2[m][n] = mfma16(aq[m], bk2[n], acc2[m][n]);
  }

  __syncthreads();
  #pragma unroll
  for (int m = 0; m < 8; ++m)
    #pragma unroll
    for (int n = 0; n < 4; ++n)
      #pragma unroll
      for (int r4 = 0; r4 < 4; ++r4) {
        const int row = m*16 + ((lane >> 4) << 2) + r4;
        const int ch  = (w*4 + n) ^ ((row >> 2) & 3) ^ (w >> 1);
        *(ushort*)(lds + row*1024 + ch*32 + fr*2) = f2h(acc2[m][n][r4]);
      }
  __syncthreads();

  const int r = t >> 2, qd = t & 3;
  const ushort* hrow = hb + ((size_t)b*SEQ + r)*DMODEL + qd*128;
  uint4 vc[16];
  float s = 0.f, q2 = 0.f;
  #pragma unroll
  for (int j = 0; j < 8; ++j) {
    const int ch = (qd*8 + j) ^ ((r >> 2) & 3) ^ qd;
    const uint4 d0 = *(const uint4*)(lds + r*1024 + ch*32);
    const uint4 d1 = *(const uint4*)(lds + r*1024 + ch*32 + 16);
    const uint4 h0 = *(const uint4*)(hrow + j*16);
    const uint4 h1 = *(const uint4*)(hrow + j*16 + 8);
    uint4 v0, v1;
    #pragma unroll
    for (int c = 0; c < 4; ++c) {
      float a0 = h2f((ushort)((&h0.x)[c] & 0xffffu)) + h2f((ushort)((&d0.x)[c] & 0xffffu));
      float a1 = h2f((ushort)((&h0.x)[c] >> 16))     + h2f((ushort)((&d0.x)[c] >> 16));
      float b0 = h2f((ushort)((&h1.x)[c] & 0xffffu)) + h2f((ushort)((&d1.x)[c] & 0xffffu));
      float b1 = h2f((ushort)((&h1.x)[c] >> 16))     + h2f((ushort)((&d1.x)[c] >> 16));
      s += a0 + a1 + b0 + b1;
      q2 += a0*a0 + a1*a1 + b0*b0 + b1*b1;
      (&v0.x)[c] = (uint)f2h(a0) | ((uint)f2h(a1) << 16);
      (&v1.x)[c] = (uint)f2h(b0) | ((uint)f2h(b1) << 16);
    }
    vc[2*j] = v0; vc[2*j+1] = v1;
  }
  #pragma unroll
  for (int off = 32; off > 0; off >>= 1) {
    s  += __shfl_down(s, off);
    q2 += __shfl_down(q2, off);
  }
  if (lane == 0) { red_[w] = s; redq_[w] = q2; }
  __syncthreads();
  if (t == 0) {
    float S = 0.f, Q = 0.f;
    #pragma unroll
    for (int i = 0; i < 8; ++i) { S += red_[i]; Q += redq_[i]; }
    const float mean = S * (1.0f/65536.0f);
    stat_[0] = mean;
    stat_[1] = rsqrtf(Q * (1.0f/65536.0f) - mean*mean + 1e-5f);
  }
  __syncthreads();
  const float mean = stat_[0], rstd = stat_[1];
  ushort* orow = hb + ((size_t)b*SEQ + r)*DMODEL + qd*128;
  #pragma unroll
  for (int j = 0; j < 16; ++j) {
    const uint4 u = vc[j];
    uint4 o;
    #pragma unroll
    for (int c = 0; c < 4; ++c) {
      const float o0 = (h2f((ushort)((&u.x)[c] & 0xffffu)) - mean) * rstd;
      const float o1 = (h2f((ushort)((&u.x)[c] >> 16))     - mean) * rstd;
      (&o.x)[c] = (uint)f2h(o0) | ((uint)f2h(o1) << 16);
    }
    *(uint4*)(orow + j*8) = o;
  }
}

// ---------------- fused FF2 + residual-LN2 (r14 form) ----------------

template<bool FINAL>
__global__ __launch_bounds__(512, 1) void gemm_f(
    const ushort* __restrict__ A, const ushort* __restrict__ Bt,
    const float* __restrict__ bias, ushort* __restrict__ hb, float* __restrict__ hf) {
  __shared__ __align__(16) char lds[131072];
  __shared__ float red_[8], redq_[8], stat_[2];
  constexpr int K = 2048, NKT = 64;
  const int t = threadIdx.x;
  const int lane = t & 63, w = t >> 6;
  const int bm = blockIdx.x;
  const int fr = lane & 15;
  const int cxor = (((lane >> 4) ^ ((fr >> 1) & 3)) << 4);

  float bias_r[4];
  #pragma unroll
  for (int n = 0; n < 4; ++n) bias_r[n] = bias[w*64 + n*16 + fr];
  asm volatile("" : "+v"(bias_r[0]), "+v"(bias_r[1]), "+v"(bias_r[2]), "+v"(bias_r[3]));

  const int srow = t >> 2;
  const int scc  = (t & 3) ^ ((t >> 3) & 3);
  const ushort* aSrc = A  + ((size_t)bm*128 + srow)*K + scc*8;
  const ushort* bSrc = Bt + (size_t)srow*K + scc*8;

  auto stage = [&](int j, int slot) {
    char* dst = lds + slot*40960 + t*16;
    load_lds16(aSrc + j*32, dst);
    #pragma unroll
    for (int i = 0; i < 4; ++i)
      load_lds16(bSrc + (size_t)(i*128)*K + j*32, dst + 8192 + i*8192);
  };

  f32x4 acc[8][4] = {};

  stage(0, 0); stage(1, 1);
  asm volatile("s_waitcnt vmcnt(5)" ::: "memory");
  __builtin_amdgcn_s_barrier();

  int rs = 0, ss = 2;
  #pragma unroll 1
  for (int kt = 0; kt < NKT; ++kt) {
    const char* sl = lds + rs*40960;
    hfrag a[8], b[4];
    #pragma unroll
    for (int m = 0; m < 8; ++m)
      a[m] = *(const hfrag*)(sl + (m*16 + fr)*64 + cxor);
    #pragma unroll
    for (int n = 0; n < 4; ++n)
      b[n] = *(const hfrag*)(sl + 8192 + (w*64 + n*16 + fr)*64 + cxor);
    if (kt + 2 < NKT) stage(kt + 2, ss);
    __builtin_amdgcn_s_setprio(1);
    #pragma unroll
    for (int m = 0; m < 8; ++m)
      #pragma unroll
      for (int n = 0; n < 4; ++n)
        acc[m][n] = mfma16(a[m], b[n], acc[m][n]);
    __builtin_amdgcn_s_setprio(0);
    if (kt + 2 < NKT) {
      asm volatile("s_waitcnt vmcnt(5)" ::: "memory");
    } else if (kt + 2 == NKT) {
      asm volatile("s_waitcnt vmcnt(0)" ::: "memory");
    }
    if (kt + 1 < NKT) __builtin_amdgcn_s_barrier();
    rs = (rs == 2) ? 0 : rs + 1;
    ss = (ss == 2) ? 0 : ss + 1;
  }

  __syncthreads();
  #pragma unroll
  for (int m = 0; m < 8; ++m)
    #pragma unroll
    for (int n = 0; n < 4; ++n)
      #pragma unroll
      for (int r4 = 0; r4 < 4; ++r4) {
        const int row = m*16 + ((lane >> 4) << 2) + r4;
        const int ch  = (w*4 + n) ^ ((row >> 2) & 3) ^ (w >> 1);
        *(ushort*)(lds + row*1024 + ch*32 + fr*2) = f2h(acc[m][n][r4] + bias_r[n]);
      }
  __syncthreads();

  const int r = t >> 2, qd = t & 3;
  const ushort* hrow = hb + ((size_t)bm*SEQ + r)*DMODEL + qd*128;
  uint4 vc[16];
  float s = 0.f, q2 = 0.f;
  #pragma unroll
  for (int j = 0; j < 8; ++j) {
    const int ch = (qd*8 + j) ^ ((r >> 2) & 3) ^ qd;
    const uint4 d0 = *(const uint4*)(lds + r*1024 + ch*32);
    const uint4 d1 = *(const uint4*)(lds + r*1024 + ch*32 + 16);
    const uint4 h0 = *(const uint4*)(hrow + j*16);
    const uint4 h1 = *(const uint4*)(hrow + j*16 + 8);
    uint4 v0, v1;
    #pragma unroll
    for (int c = 0; c < 4; ++c) {
      float a0 = h2f((ushort)((&h0.x)[c] & 0xffffu)) + h2f((ushort)((&d0.x)[c] & 0xffffu));
      float a1 = h2f((ushort)((&h0.x)[c] >> 16))     + h2f((ushort)((&d0.x)[c] >> 16));
      float b0 = h2f((ushort)((&h1.x)[c] & 0xffffu)) + h2f((ushort)((&d1.x)[c] & 0xffffu));
      float b1 = h2f((ushort)((&h1.x)[c] >> 16))     + h2f((ushort)((&d1.x)[c] >> 16));
      s += a0 + a1 + b0 + b1;
      q2 += a0*a0 + a1*a1 + b0*b0 + b1*b1;
      (&v0.x)[c] = (uint)f2h(a0) | ((uint)f2h(a1) << 16);
      (&v1.x)[c] = (uint)f2h(b0) | ((uint)f2h(b1) << 16);
    }
    vc[2*j] = v0; vc[2*j+1] = v1;
  }
  #pragma unroll
  for (int off = 32; off > 0; off >>= 1) {
    s  += __shfl_down(s, off);
    q2 += __shfl_down(q2, off);
  }
  if (lane == 0) { red_[w] = s; redq_[w] = q2; }
  __syncthreads();
  if (t == 0) {
    float S = 0.f, Q = 0.f;
    #pragma unroll
    for (int i = 0; i < 8; ++i) { S += red_[i]; Q += redq_[i]; }
    const float mean = S * (1.0f/65536.0f);
    stat_[0] = mean;
    stat_[1] = rsqrtf(Q * (1.0f/65536.0f) - mean*mean + 1e-5f);
  }
  __syncthreads();
  const float mean = stat_[0], rstd = stat_[1];
  if constexpr (FINAL) {
    float* frow = hf + ((size_t)bm*SEQ + r)*DMODEL + qd*128;
    #pragma unroll
    for (int j = 0; j < 16; ++j) {
      const uint4 u = vc[j];
      f32x4 o0, o1;
      #pragma unroll
      for (int c = 0; c < 2; ++c) {
        o0[2*c]   = (h2f((ushort)((&u.x)[c] & 0xffffu)) - mean) * rstd;
        o0[2*c+1] = (h2f((ushort)((&u.x)[c] >> 16))     - mean) * rstd;
        o1[2*c]   = (h2f((ushort)((&u.x)[c+2] & 0xffffu)) - mean) * rstd;
        o1[2*c+1] = (h2f((ushort)((&u.x)[c+2] >> 16))     - mean) * rstd;
      }
      *(f32x4*)(frow + j*8)     = o0;
      *(f32x4*)(frow + j*8 + 4) = o1;
    }
  } else {
    ushort* orow = hb + ((size_t)bm*SEQ + r)*DMODEL + qd*128;
    #pragma unroll
    for (int j = 0; j < 16; ++j) {
      const uint4 u = vc[j];
      uint4 o;
      #pragma unroll
      for (int c = 0; c < 4; ++c) {
        const float o0 = (h2f((ushort)((&u.x)[c] & 0xffffu)) - mean) * rstd;
        const float o1 = (h2f((ushort)((&u.x)[c] >> 16))     - mean) * rstd;
        (&o.x)[c] = (uint)f2h(o0) | ((uint)f2h(o1) << 16);
      }
      *(uint4*)(orow + j*8) = o;
    }
  }
}

// ---------------- driver ----------------

extern "C" void kernel_launch(void* const* d_in, const int* in_sizes, int n_in,
                              void* d_out, int out_size, void* d_ws, size_t ws_size,
                              hipStream_t stream) {
  const int*   x   = (const int*)d_in[0];
  const float* emb = (const float*)d_in[1];
  const float* Wq  = (const float*)d_in[2];
  const float* bq  = (const float*)d_in[3];
  const float* Wk  = (const float*)d_in[4];
  const float* bk  = (const float*)d_in[5];
  const float* Wv  = (const float*)d_in[6];
  const float* bv  = (const float*)d_in[7];
  const float* W1  = (const float*)d_in[8];
  const float* b1  = (const float*)d_in[9];
  const float* W2  = (const float*)d_in[10];
  const float* b2  = (const float*)d_in[11];
  float* h = (float*)d_out;

  char* p = (char*)d_ws;
  size_t off = 0;
  auto alloc = [&](size_t bytes) { char* r = p + off; off += (bytes + 255) & ~(size_t)255; return r; };
  ushort* Wqkv_t = (ushort*)alloc((size_t)NLAYERS*1536*512*2);
  ushort* W1t    = (ushort*)alloc((size_t)NLAYERS*INNER*512*2);
  ushort* W2t    = (ushort*)alloc((size_t)NLAYERS*512*INNER*2);
  float*  biasq  = (float*)alloc((size_t)NLAYERS*1536*4);
  ushort* hbf    = (ushort*)alloc((size_t)NTOK*512*2);
  ushort* big    = (ushort*)alloc((size_t)NTOK*2048*2);  // qkv (1536) / FF inner (2048)

  prep_qkv<<<(NLAYERS*1536*512 + 255)/256, 256, 0, stream>>>(Wq, Wk, Wv, bq, bk, bv, Wqkv_t, biasq);
  prep_w1<<<(NLAYERS*INNER*512 + 255)/256, 256, 0, stream>>>(W1, W1t);
  prep_w2<<<(NLAYERS*512*INNER + 255)/256, 256, 0, stream>>>(W2, W2t);
  embed_kernel<<<NTOK, 256, 0, stream>>>(x, emb, hbf);

  for (int l = 0; l < NLAYERS; ++l) {
    // QKV: [32768,512] x [1536,512]^T -> dense [32768,1536] f16
    gemm_2<512,0><<<768, 512, 0, stream>>>(
        hbf, Wqkv_t + (size_t)l*1536*512, biasq + (size_t)l*1536, big, 1536, 6);
    // attention + LN1 (fused): hb = LN(hb + attn)
    attn_ln<<<BATCH, 512, 0, stream>>>(big, hbf);
    // FF1: [32768,512] x [2048,512]^T -> relu -> big [32768,2048]
    gemm_2<512,1><<<1024, 512, 0, stream>>>(
        hbf, W1t + (size_t)l*INNER*512, b1 + (size_t)l*INNER, big, 2048, 8);
    // FF2 + LN2 (fused): hb = LN(hb + ff2); final layer writes f32 out
    if (l == NLAYERS-1) {
      gemm_f<true><<<BATCH, 512, 0, stream>>>(
          big, W2t + (size_t)l*512*INNER, b2 + (size_t)l*512, hbf, h);
    } else {
      gemm_f<false><<<BATCH, 512, 0, stream>>>(
          big, W2t + (size_t)l*512*INNER, b2 + (size_t)l*512, hbf, nullptr);
    }
  }
}

// Round 17
// 1672.325 us; speedup vs baseline: 1.0248x; 1.0248x over previous
//
#include <hip/hip_runtime.h>
#include <stdint.h>

#define NLAYERS 6
#define DMODEL  512
#define NHEADS  8
#define HDIM    64
#define INNER   2048
#define SEQ     128
#define BATCH   256
#define NTOK    (BATCH*SEQ)

typedef __attribute__((ext_vector_type(4))) float f32x4;
typedef __attribute__((ext_vector_type(8))) _Float16 hfrag;

typedef const __attribute__((address_space(1))) void* gas1p;
typedef __attribute__((address_space(3))) void* las3p;

__device__ __forceinline__ void load_lds16(const void* g, void* l) {
  __builtin_amdgcn_global_load_lds((gas1p)(uintptr_t)g, (las3p)(uint32_t)(uintptr_t)l, 16, 0, 0);
}

__device__ __forceinline__ ushort f2h(float f) {
  return __builtin_bit_cast(ushort, (_Float16)f);
}
__device__ __forceinline__ float h2f(ushort u) {
  return (float)__builtin_bit_cast(_Float16, u);
}

__device__ __forceinline__ f32x4 mfma16(hfrag a, hfrag b, f32x4 c) {
  return __builtin_amdgcn_mfma_f32_16x16x32_f16(a, b, c, 0, 0, 0);
}

// ---------------- weight prep (f32 -> f16, transposed to [N][K]) ----------------

__global__ void prep_qkv(const float* __restrict__ Wq, const float* __restrict__ Wk,
                         const float* __restrict__ Wv, const float* __restrict__ bq,
                         const float* __restrict__ bk, const float* __restrict__ bv,
                         ushort* __restrict__ Wt, float* __restrict__ biasq) {
  int idx = blockIdx.x*256 + threadIdx.x;
  if (idx >= NLAYERS*1536*512) return;
  const int k = idx & 511;
  const int n = (idx >> 9) % 1536;
  const int l = idx / (1536*512);
  const int which = n >> 9, hh = (n >> 6) & 7, e = n & 63;
  const float* W = (which == 0) ? Wq : ((which == 1) ? Wk : Wv);
  Wt[idx] = f2h(W[(((size_t)l*NHEADS + hh)*DMODEL + k)*HDIM + e]);
  if (k == 0) {
    const float* bb = (which == 0) ? bq : ((which == 1) ? bk : bv);
    biasq[l*1536 + n] = bb[((size_t)l*NHEADS + hh)*HDIM + e];
  }
}

__global__ void prep_w1(const float* __restrict__ W1, ushort* __restrict__ W1t) {
  int idx = blockIdx.x*256 + threadIdx.x;
  if (idx >= NLAYERS*INNER*512) return;
  const int k = idx & 511;
  const int n = (idx >> 9) % INNER;
  const int l = idx / (INNER*512);
  W1t[idx] = f2h(W1[((size_t)l*DMODEL + k)*INNER + n]);
}

__global__ void prep_w2(const float* __restrict__ W2, ushort* __restrict__ W2t) {
  int idx = blockIdx.x*256 + threadIdx.x;
  if (idx >= NLAYERS*512*INNER) return;
  const int k = idx & 2047;
  const int n = (idx >> 11) & 511;
  const int l = idx / (512*INNER);
  W2t[idx] = f2h(W2[((size_t)l*INNER + k)*DMODEL + n]);
}

// ---------------- embedding + positional encoding (f16 residual stream) ----------------

__global__ void embed_kernel(const int* __restrict__ x, const float* __restrict__ emb,
                             ushort* __restrict__ hb) {
  const int t = blockIdx.x;       // token 0..32767
  const int i = threadIdx.x;      // pair 0..255
  const int s = t & (SEQ-1);
  const int tok = x[t];
  const float freq = expf(-(float)i * (9.210340371976184f / 256.0f)); // 10000^(-i/256)
  const float th = (float)s * freq;
  const float sn = sinf(th), cs = cosf(th);
  const size_t base = (size_t)t*DMODEL;
  const float v0 = emb[(size_t)tok*DMODEL + 2*i]     + sn;
  const float v1 = emb[(size_t)tok*DMODEL + 2*i + 1] + cs;
  *(uint*)(hb + base + 2*i) = (uint)f2h(v0) | ((uint)f2h(v1) << 16);
}

// ---------------- 128x256 tiled f16 MFMA GEMM, ring-3, ONE barrier/K-tile -------
// r11 K-loop verbatim (proven: 0 conflicts, no spill). Epilogue: 2 m-steps
// per barrier pair (r15 variant, individually positive).
// EPI: 0 = bias->f16, 1 = bias+relu->f16

template<int K, int EPI>
__global__ __launch_bounds__(256, 2) void gemm_t(
    const ushort* __restrict__ A, const ushort* __restrict__ Bt,
    const float* __restrict__ bias, ushort* __restrict__ outb,
    const int ldc, const int nbn) {
  __shared__ __align__(16) char lds[73728];
  constexpr int NKT = K / 32;
  const int t = threadIdx.x;
  const int lane = t & 63, wc = t >> 6;
  const int cpx = (int)gridDim.x >> 3;
  const int wg  = ((int)blockIdx.x & 7) * cpx + ((int)blockIdx.x >> 3);
  const int bm = wg / nbn, bn = wg % nbn;

  const int fr = lane & 15;
  const int cxor = (((lane >> 4) ^ ((fr >> 1) & 3)) << 4);

  float bias_r[4];
  #pragma unroll
  for (int n = 0; n < 4; ++n) bias_r[n] = bias[bn*256 + wc*64 + n*16 + fr];
  asm volatile("" : "+v"(bias_r[0]), "+v"(bias_r[1]), "+v"(bias_r[2]), "+v"(bias_r[3]));

  const int srow = t >> 2;
  const int scc  = (t & 3) ^ ((t >> 3) & 3);
  const ushort* aSrc = A  + ((size_t)bm*128 + srow)*K + scc*8;
  const ushort* bSrc = Bt + ((size_t)bn*256 + srow)*K + scc*8;

  auto stage_t = [&](int j, int slot) {
    char* dst = lds + slot*24576 + t*16;
    const ushort* as = aSrc + j*32;
    load_lds16(as,                  dst);
    load_lds16(as + (size_t)64*K,   dst + 4096);
    const ushort* bs = bSrc + j*32;
    #pragma unroll
    for (int i = 0; i < 4; ++i)
      load_lds16(bs + (size_t)(i*64)*K, dst + 8192 + i*4096);
  };

  f32x4 acc[8][4] = {};

  stage_t(0, 0); stage_t(1, 1);
  asm volatile("s_waitcnt vmcnt(6)" ::: "memory");
  __builtin_amdgcn_s_barrier();

  int rs = 0, ss = 2;
  #pragma unroll 1
  for (int kt = 0; kt < NKT; ++kt) {
    const char* sl = lds + rs*24576;
    hfrag a[8], b[4];
    #pragma unroll
    for (int m = 0; m < 8; ++m)
      a[m] = *(const hfrag*)(sl + (m*16 + fr)*64 + cxor);
    #pragma unroll
    for (int n = 0; n < 4; ++n)
      b[n] = *(const hfrag*)(sl + 8192 + (wc*64 + n*16 + fr)*64 + cxor);
    if (kt + 2 < NKT) stage_t(kt + 2, ss);
    __builtin_amdgcn_s_setprio(1);
    #pragma unroll
    for (int m = 0; m < 8; ++m)
      #pragma unroll
      for (int n = 0; n < 4; ++n)
        acc[m][n] = mfma16(a[m], b[n], acc[m][n]);
    __builtin_amdgcn_s_setprio(0);
    if (kt + 2 < NKT) {
      asm volatile("s_waitcnt vmcnt(6)" ::: "memory");
    } else if (kt + 2 == NKT) {
      asm volatile("s_waitcnt vmcnt(0)" ::: "memory");
    }
    if (kt + 1 < NKT) __builtin_amdgcn_s_barrier();
    rs = (rs == 2) ? 0 : rs + 1;
    ss = (ss == 2) ? 0 : ss + 1;
  }

  // coalesced epilogue: 2 m-steps (32 rows, 16 KB) per barrier pair.
  #pragma unroll
  for (int mm = 0; mm < 4; ++mm) {
    __syncthreads();
    #pragma unroll
    for (int mi = 0; mi < 2; ++mi) {
      const int m = mm*2 + mi;
      #pragma unroll
      for (int n = 0; n < 4; ++n) {
        const int cc16 = wc*4 + n;
        #pragma unroll
        for (int r4 = 0; r4 < 4; ++r4) {
          const int rr = ((lane >> 4) << 2) + r4;            // 0..15
          float v = acc[m][n][r4] + bias_r[n];
          if constexpr (EPI == 1) v = fmaxf(v, 0.0f);
          *(ushort*)(lds + (mi*16 + rr)*512 + ((cc16 ^ (rr >> 2)) << 5) + fr*2) = f2h(v);
        }
      }
    }
    __syncthreads();
    #pragma unroll
    for (int pr = 0; pr < 2; ++pr) {
      const int lr = (t >> 4) + pr*16;                       // 0..31
      const int er16 = lr & 15;
      ushort* gp = outb + (size_t)(bm*128 + mm*32 + lr)*ldc + bn*256;
      #pragma unroll
      for (int pc = 0; pc < 2; ++pc) {
        const int cj = (t & 15) + pc*16;
        const uint4 v = *(const uint4*)(lds + lr*512 + (((cj >> 1) ^ (er16 >> 2)) << 5) + ((cj & 1) << 4));
        *(uint4*)(gp + cj*8) = v;
      }
    }
  }
}

// ---------------- fused attention + residual-LN1 (r14 form, no hoist) ----------------

__global__ __launch_bounds__(512, 1) void attn_ln(
    const ushort* __restrict__ qkv, ushort* __restrict__ hb) {
  __shared__ __align__(16) char lds[131072];
  __shared__ float red_[8], redq_[8], stat_[2];
  const int t = threadIdx.x;
  const int w = t >> 6, lane = t & 63;
  const int b = blockIdx.x, h = w;
  const int fr = lane & 15;
  const ushort* tokbase = qkv + (size_t)b*SEQ*1536;
  ushort* wl  = (ushort*)(lds + w*16384);
  ushort* kch = wl;
  ushort* vch = wl + 2048;

  f32x4 acc1[4][4] = {};
  #pragma unroll 1
  for (int sb = 0; sb < 4; ++sb) {
    const int s0 = sb*32;
    const int sr = lane >> 1;
    #pragma unroll
    for (int i = 0; i < 4; ++i) {
      const int cc  = i*2 + (lane & 1);
      const int ccs = cc ^ (sr & 7);
      const ushort* g = tokbase + (size_t)(s0+sr)*1536 + h*64 + cc*8;
      *(uint4*)(kch + sr*64 + ccs*8) = *(const uint4*)(g + 512);
      *(uint4*)(vch + sr*64 + ccs*8) = *(const uint4*)(g + 1024);
    }
    hfrag ak[4], av[4];
    #pragma unroll
    for (int m = 0; m < 4; ++m) {
      const int e1 = m*16 + (lane & 15);
      const int ccb = e1 >> 3, el = e1 & 7;
      #pragma unroll
      for (int j = 0; j < 8; ++j) {
        const int s = (lane >> 4)*8 + j;
        ak[m][j] = __builtin_bit_cast(_Float16, kch[s*64 + ((ccb ^ (s & 7))*8) + el]);
        av[m][j] = __builtin_bit_cast(_Float16, vch[s*64 + ((ccb ^ (s & 7))*8) + el]);
      }
    }
    #pragma unroll
    for (int m = 0; m < 4; ++m)
      #pragma unroll
      for (int n = 0; n < 4; ++n)
        acc1[m][n] = mfma16(ak[m], av[n], acc1[m][n]);
  }

  ushort* tv = wl;
  #pragma unroll
  for (int m = 0; m < 4; ++m)
    #pragma unroll
    for (int n = 0; n < 4; ++n)
      #pragma unroll
      for (int r4 = 0; r4 < 4; ++r4) {
        const int e1 = m*16 + (lane >> 4)*4 + r4;
        const int e2 = n*16 + (lane & 15);
        tv[e2*72 + e1] = f2h(acc1[m][n][r4] * 0.125f);
      }

  f32x4 acc2[8][4] = {};
  #pragma unroll
  for (int eb = 0; eb < 2; ++eb) {
    const int e1b = eb*32 + (lane >> 4)*8;
    hfrag aq[8], bk2[4];
    #pragma unroll
    for (int m = 0; m < 8; ++m) {
      const int s = m*16 + (lane & 15);
      aq[m] = *(const hfrag*)(tokbase + (size_t)s*1536 + h*64 + e1b);
    }
    #pragma unroll
    for (int n = 0; n < 4; ++n) {
      const int e2 = n*16 + (lane & 15);
      bk2[n] = *(const hfrag*)(tv + e2*72 + e1b);
    }
    #pragma unroll
    for (int m = 0; m < 8; ++m)
      #pragma unroll
      for (int n = 0; n < 4; ++n)
        acc2[m][n] = mfma16(aq[m], bk2[n], acc2[m][n]);
  }

  __syncthreads();
  #pragma unroll
  for (int m = 0; m < 8; ++m)
    #pragma unroll
    for (int n = 0; n < 4; ++n)
      #pragma unroll
      for (int r4 = 0; r4 < 4; ++r4) {
        const int row = m*16 + ((lane >> 4) << 2) + r4;
        const int ch  = (w*4 + n) ^ ((row >> 2) & 3) ^ (w >> 1);
        *(ushort*)(lds + row*1024 + ch*32 + fr*2) = f2h(acc2[m][n][r4]);
      }
  __syncthreads();

  const int r = t >> 2, qd = t & 3;
  const ushort* hrow = hb + ((size_t)b*SEQ + r)*DMODEL + qd*128;
  uint4 vc[16];
  float s = 0.f, q2 = 0.f;
  #pragma unroll
  for (int j = 0; j < 8; ++j) {
    const int ch = (qd*8 + j) ^ ((r >> 2) & 3) ^ qd;
    const uint4 d0 = *(const uint4*)(lds + r*1024 + ch*32);
    const uint4 d1 = *(const uint4*)(lds + r*1024 + ch*32 + 16);
    const uint4 h0 = *(const uint4*)(hrow + j*16);
    const uint4 h1 = *(const uint4*)(hrow + j*16 + 8);
    uint4 v0, v1;
    #pragma unroll
    for (int c = 0; c < 4; ++c) {
      float a0 = h2f((ushort)((&h0.x)[c] & 0xffffu)) + h2f((ushort)((&d0.x)[c] & 0xffffu));
      float a1 = h2f((ushort)((&h0.x)[c] >> 16))     + h2f((ushort)((&d0.x)[c] >> 16));
      float b0 = h2f((ushort)((&h1.x)[c] & 0xffffu)) + h2f((ushort)((&d1.x)[c] & 0xffffu));
      float b1 = h2f((ushort)((&h1.x)[c] >> 16))     + h2f((ushort)((&d1.x)[c] >> 16));
      s += a0 + a1 + b0 + b1;
      q2 += a0*a0 + a1*a1 + b0*b0 + b1*b1;
      (&v0.x)[c] = (uint)f2h(a0) | ((uint)f2h(a1) << 16);
      (&v1.x)[c] = (uint)f2h(b0) | ((uint)f2h(b1) << 16);
    }
    vc[2*j] = v0; vc[2*j+1] = v1;
  }
  #pragma unroll
  for (int off = 32; off > 0; off >>= 1) {
    s  += __shfl_down(s, off);
    q2 += __shfl_down(q2, off);
  }
  if (lane == 0) { red_[w] = s; redq_[w] = q2; }
  __syncthreads();
  if (t == 0) {
    float S = 0.f, Q = 0.f;
    #pragma unroll
    for (int i = 0; i < 8; ++i) { S += red_[i]; Q += redq_[i]; }
    const float mean = S * (1.0f/65536.0f);
    stat_[0] = mean;
    stat_[1] = rsqrtf(Q * (1.0f/65536.0f) - mean*mean + 1e-5f);
  }
  __syncthreads();
  const float mean = stat_[0], rstd = stat_[1];
  ushort* orow = hb + ((size_t)b*SEQ + r)*DMODEL + qd*128;
  #pragma unroll
  for (int j = 0; j < 16; ++j) {
    const uint4 u = vc[j];
    uint4 o;
    #pragma unroll
    for (int c = 0; c < 4; ++c) {
      const float o0 = (h2f((ushort)((&u.x)[c] & 0xffffu)) - mean) * rstd;
      const float o1 = (h2f((ushort)((&u.x)[c] >> 16))     - mean) * rstd;
      (&o.x)[c] = (uint)f2h(o0) | ((uint)f2h(o1) << 16);
    }
    *(uint4*)(orow + j*8) = o;
  }
}

// ---------------- fused FF2 + residual-LN2 (r14 form, no hoist) ----------------

template<bool FINAL>
__global__ __launch_bounds__(512, 1) void gemm_f(
    const ushort* __restrict__ A, const ushort* __restrict__ Bt,
    const float* __restrict__ bias, ushort* __restrict__ hb, float* __restrict__ hf) {
  __shared__ __align__(16) char lds[131072];
  __shared__ float red_[8], redq_[8], stat_[2];
  constexpr int K = 2048, NKT = 64;
  const int t = threadIdx.x;
  const int lane = t & 63, w = t >> 6;
  const int bm = blockIdx.x;
  const int fr = lane & 15;
  const int cxor = (((lane >> 4) ^ ((fr >> 1) & 3)) << 4);

  float bias_r[4];
  #pragma unroll
  for (int n = 0; n < 4; ++n) bias_r[n] = bias[w*64 + n*16 + fr];
  asm volatile("" : "+v"(bias_r[0]), "+v"(bias_r[1]), "+v"(bias_r[2]), "+v"(bias_r[3]));

  const int srow = t >> 2;
  const int scc  = (t & 3) ^ ((t >> 3) & 3);
  const ushort* aSrc = A  + ((size_t)bm*128 + srow)*K + scc*8;
  const ushort* bSrc = Bt + (size_t)srow*K + scc*8;

  auto stage = [&](int j, int slot) {
    char* dst = lds + slot*40960 + t*16;
    load_lds16(aSrc + j*32, dst);
    #pragma unroll
    for (int i = 0; i < 4; ++i)
      load_lds16(bSrc + (size_t)(i*128)*K + j*32, dst + 8192 + i*8192);
  };

  f32x4 acc[8][4] = {};

  stage(0, 0); stage(1, 1);
  asm volatile("s_waitcnt vmcnt(5)" ::: "memory");
  __builtin_amdgcn_s_barrier();

  int rs = 0, ss = 2;
  #pragma unroll 1
  for (int kt = 0; kt < NKT; ++kt) {
    const char* sl = lds + rs*40960;
    hfrag a[8], b[4];
    #pragma unroll
    for (int m = 0; m < 8; ++m)
      a[m] = *(const hfrag*)(sl + (m*16 + fr)*64 + cxor);
    #pragma unroll
    for (int n = 0; n < 4; ++n)
      b[n] = *(const hfrag*)(sl + 8192 + (w*64 + n*16 + fr)*64 + cxor);
    if (kt + 2 < NKT) stage(kt + 2, ss);
    __builtin_amdgcn_s_setprio(1);
    #pragma unroll
    for (int m = 0; m < 8; ++m)
      #pragma unroll
      for (int n = 0; n < 4; ++n)
        acc[m][n] = mfma16(a[m], b[n], acc[m][n]);
    __builtin_amdgcn_s_setprio(0);
    if (kt + 2 < NKT) {
      asm volatile("s_waitcnt vmcnt(5)" ::: "memory");
    } else if (kt + 2 == NKT) {
      asm volatile("s_waitcnt vmcnt(0)" ::: "memory");
    }
    if (kt + 1 < NKT) __builtin_amdgcn_s_barrier();
    rs = (rs == 2) ? 0 : rs + 1;
    ss = (ss == 2) ? 0 : ss + 1;
  }

  __syncthreads();
  #pragma unroll
  for (int m = 0; m < 8; ++m)
    #pragma unroll
    for (int n = 0; n < 4; ++n)
      #pragma unroll
      for (int r4 = 0; r4 < 4; ++r4) {
        const int row = m*16 + ((lane >> 4) << 2) + r4;
        const int ch  = (w*4 + n) ^ ((row >> 2) & 3) ^ (w >> 1);
        *(ushort*)(lds + row*1024 + ch*32 + fr*2) = f2h(acc[m][n][r4] + bias_r[n]);
      }
  __syncthreads();

  const int r = t >> 2, qd = t & 3;
  const ushort* hrow = hb + ((size_t)bm*SEQ + r)*DMODEL + qd*128;
  uint4 vc[16];
  float s = 0.f, q2 = 0.f;
  #pragma unroll
  for (int j = 0; j < 8; ++j) {
    const int ch = (qd*8 + j) ^ ((r >> 2) & 3) ^ qd;
    const uint4 d0 = *(const uint4*)(lds + r*1024 + ch*32);
    const uint4 d1 = *(const uint4*)(lds + r*1024 + ch*32 + 16);
    const uint4 h0 = *(const uint4*)(hrow + j*16);
    const uint4 h1 = *(const uint4*)(hrow + j*16 + 8);
    uint4 v0, v1;
    #pragma unroll
    for (int c = 0; c < 4; ++c) {
      float a0 = h2f((ushort)((&h0.x)[c] & 0xffffu)) + h2f((ushort)((&d0.x)[c] & 0xffffu));
      float a1 = h2f((ushort)((&h0.x)[c] >> 16))     + h2f((ushort)((&d0.x)[c] >> 16));
      float b0 = h2f((ushort)((&h1.x)[c] & 0xffffu)) + h2f((ushort)((&d1.x)[c] & 0xffffu));
      float b1 = h2f((ushort)((&h1.x)[c] >> 16))     + h2f((ushort)((&d1.x)[c] >> 16));
      s += a0 + a1 + b0 + b1;
      q2 += a0*a0 + a1*a1 + b0*b0 + b1*b1;
      (&v0.x)[c] = (uint)f2h(a0) | ((uint)f2h(a1) << 16);
      (&v1.x)[c] = (uint)f2h(b0) | ((uint)f2h(b1) << 16);
    }
    vc[2*j] = v0; vc[2*j+1] = v1;
  }
  #pragma unroll
  for (int off = 32; off > 0; off >>= 1) {
    s  += __shfl_down(s, off);
    q2 += __shfl_down(q2, off);
  }
  if (lane == 0) { red_[w] = s; redq_[w] = q2; }
  __syncthreads();
  if (t == 0) {
    float S = 0.f, Q = 0.f;
    #pragma unroll
    for (int i = 0; i < 8; ++i) { S += red_[i]; Q += redq_[i]; }
    const float mean = S * (1.0f/65536.0f);
    stat_[0] = mean;
    stat_[1] = rsqrtf(Q * (1.0f/65536.0f) - mean*mean + 1e-5f);
  }
  __syncthreads();
  const float mean = stat_[0], rstd = stat_[1];
  if constexpr (FINAL) {
    float* frow = hf + ((size_t)bm*SEQ + r)*DMODEL + qd*128;
    #pragma unroll
    for (int j = 0; j < 16; ++j) {
      const uint4 u = vc[j];
      f32x4 o0, o1;
      #pragma unroll
      for (int c = 0; c < 2; ++c) {
        o0[2*c]   = (h2f((ushort)((&u.x)[c] & 0xffffu)) - mean) * rstd;
        o0[2*c+1] = (h2f((ushort)((&u.x)[c] >> 16))     - mean) * rstd;
        o1[2*c]   = (h2f((ushort)((&u.x)[c+2] & 0xffffu)) - mean) * rstd;
        o1[2*c+1] = (h2f((ushort)((&u.x)[c+2] >> 16))     - mean) * rstd;
      }
      *(f32x4*)(frow + j*8)     = o0;
      *(f32x4*)(frow + j*8 + 4) = o1;
    }
  } else {
    ushort* orow = hb + ((size_t)bm*SEQ + r)*DMODEL + qd*128;
    #pragma unroll
    for (int j = 0; j < 16; ++j) {
      const uint4 u = vc[j];
      uint4 o;
      #pragma unroll
      for (int c = 0; c < 4; ++c) {
        const float o0 = (h2f((ushort)((&u.x)[c] & 0xffffu)) - mean) * rstd;
        const float o1 = (h2f((ushort)((&u.x)[c] >> 16))     - mean) * rstd;
        (&o.x)[c] = (uint)f2h(o0) | ((uint)f2h(o1) << 16);
      }
      *(uint4*)(orow + j*8) = o;
    }
  }
}

// ---------------- driver ----------------

extern "C" void kernel_launch(void* const* d_in, const int* in_sizes, int n_in,
                              void* d_out, int out_size, void* d_ws, size_t ws_size,
                              hipStream_t stream) {
  const int*   x   = (const int*)d_in[0];
  const float* emb = (const float*)d_in[1];
  const float* Wq  = (const float*)d_in[2];
  const float* bq  = (const float*)d_in[3];
  const float* Wk  = (const float*)d_in[4];
  const float* bk  = (const float*)d_in[5];
  const float* Wv  = (const float*)d_in[6];
  const float* bv  = (const float*)d_in[7];
  const float* W1  = (const float*)d_in[8];
  const float* b1  = (const float*)d_in[9];
  const float* W2  = (const float*)d_in[10];
  const float* b2  = (const float*)d_in[11];
  float* h = (float*)d_out;

  char* p = (char*)d_ws;
  size_t off = 0;
  auto alloc = [&](size_t bytes) { char* r = p + off; off += (bytes + 255) & ~(size_t)255; return r; };
  ushort* Wqkv_t = (ushort*)alloc((size_t)NLAYERS*1536*512*2);
  ushort* W1t    = (ushort*)alloc((size_t)NLAYERS*INNER*512*2);
  ushort* W2t    = (ushort*)alloc((size_t)NLAYERS*512*INNER*2);
  float*  biasq  = (float*)alloc((size_t)NLAYERS*1536*4);
  ushort* hbf    = (ushort*)alloc((size_t)NTOK*512*2);
  ushort* big    = (ushort*)alloc((size_t)NTOK*2048*2);  // qkv (1536) / FF inner (2048)

  prep_qkv<<<(NLAYERS*1536*512 + 255)/256, 256, 0, stream>>>(Wq, Wk, Wv, bq, bk, bv, Wqkv_t, biasq);
  prep_w1<<<(NLAYERS*INNER*512 + 255)/256, 256, 0, stream>>>(W1, W1t);
  prep_w2<<<(NLAYERS*512*INNER + 255)/256, 256, 0, stream>>>(W2, W2t);
  embed_kernel<<<NTOK, 256, 0, stream>>>(x, emb, hbf);

  for (int l = 0; l < NLAYERS; ++l) {
    // QKV: [32768,512] x [1536,512]^T -> dense [32768,1536] f16
    gemm_t<512,0><<<1536, 256, 0, stream>>>(
        hbf, Wqkv_t + (size_t)l*1536*512, biasq + (size_t)l*1536, big, 1536, 6);
    // attention + LN1 (fused): hb = LN(hb + attn)
    attn_ln<<<BATCH, 512, 0, stream>>>(big, hbf);
    // FF1: [32768,512] x [2048,512]^T -> relu -> big [32768,2048]
    gemm_t<512,1><<<2048, 256, 0, stream>>>(
        hbf, W1t + (size_t)l*INNER*512, b1 + (size_t)l*INNER, big, 2048, 8);
    // FF2 + LN2 (fused): hb = LN(hb + ff2); final layer writes f32 out
    if (l == NLAYERS-1) {
      gemm_f<true><<<BATCH, 512, 0, stream>>>(
          big, W2t + (size_t)l*512*INNER, b2 + (size_t)l*512, hbf, h);
    } else {
      gemm_f<false><<<BATCH, 512, 0, stream>>>(
          big, W2t + (size_t)l*512*INNER, b2 + (size_t)l*512, hbf, nullptr);
    }
  }
}

// Round 18
// 1644.849 us; speedup vs baseline: 1.0419x; 1.0167x over previous
//
#include <hip/hip_runtime.h>
#include <stdint.h>

#define NLAYERS 6
#define DMODEL  512
#define NHEADS  8
#define HDIM    64
#define INNER   2048
#define SEQ     128
#define BATCH   256
#define NTOK    (BATCH*SEQ)

typedef __attribute__((ext_vector_type(4))) float f32x4;
typedef __attribute__((ext_vector_type(8))) _Float16 hfrag;

typedef const __attribute__((address_space(1))) void* gas1p;
typedef __attribute__((address_space(3))) void* las3p;

__device__ __forceinline__ void load_lds16(const void* g, void* l) {
  __builtin_amdgcn_global_load_lds((gas1p)(uintptr_t)g, (las3p)(uint32_t)(uintptr_t)l, 16, 0, 0);
}

__device__ __forceinline__ ushort f2h(float f) {
  return __builtin_bit_cast(ushort, (_Float16)f);
}
__device__ __forceinline__ float h2f(ushort u) {
  return (float)__builtin_bit_cast(_Float16, u);
}

__device__ __forceinline__ f32x4 mfma16(hfrag a, hfrag b, f32x4 c) {
  return __builtin_amdgcn_mfma_f32_16x16x32_f16(a, b, c, 0, 0, 0);
}

// ---------------- weight prep (f32 -> f16, transposed to [N][K]) ----------------

__global__ void prep_qkv(const float* __restrict__ Wq, const float* __restrict__ Wk,
                         const float* __restrict__ Wv, const float* __restrict__ bq,
                         const float* __restrict__ bk, const float* __restrict__ bv,
                         ushort* __restrict__ Wt, float* __restrict__ biasq) {
  int idx = blockIdx.x*256 + threadIdx.x;
  if (idx >= NLAYERS*1536*512) return;
  const int k = idx & 511;
  const int n = (idx >> 9) % 1536;
  const int l = idx / (1536*512);
  const int which = n >> 9, hh = (n >> 6) & 7, e = n & 63;
  const float* W = (which == 0) ? Wq : ((which == 1) ? Wk : Wv);
  Wt[idx] = f2h(W[(((size_t)l*NHEADS + hh)*DMODEL + k)*HDIM + e]);
  if (k == 0) {
    const float* bb = (which == 0) ? bq : ((which == 1) ? bk : bv);
    biasq[l*1536 + n] = bb[((size_t)l*NHEADS + hh)*HDIM + e];
  }
}

__global__ void prep_w1(const float* __restrict__ W1, ushort* __restrict__ W1t) {
  int idx = blockIdx.x*256 + threadIdx.x;
  if (idx >= NLAYERS*INNER*512) return;
  const int k = idx & 511;
  const int n = (idx >> 9) % INNER;
  const int l = idx / (INNER*512);
  W1t[idx] = f2h(W1[((size_t)l*DMODEL + k)*INNER + n]);
}

__global__ void prep_w2(const float* __restrict__ W2, ushort* __restrict__ W2t) {
  int idx = blockIdx.x*256 + threadIdx.x;
  if (idx >= NLAYERS*512*INNER) return;
  const int k = idx & 2047;
  const int n = (idx >> 11) & 511;
  const int l = idx / (512*INNER);
  W2t[idx] = f2h(W2[((size_t)l*INNER + k)*DMODEL + n]);
}

// ---------------- embedding + positional encoding (f16 residual stream) ----------------

__global__ void embed_kernel(const int* __restrict__ x, const float* __restrict__ emb,
                             ushort* __restrict__ hb) {
  const int t = blockIdx.x;       // token 0..32767
  const int i = threadIdx.x;      // pair 0..255
  const int s = t & (SEQ-1);
  const int tok = x[t];
  const float freq = expf(-(float)i * (9.210340371976184f / 256.0f)); // 10000^(-i/256)
  const float th = (float)s * freq;
  const float sn = sinf(th), cs = cosf(th);
  const size_t base = (size_t)t*DMODEL;
  const float v0 = emb[(size_t)tok*DMODEL + 2*i]     + sn;
  const float v1 = emb[(size_t)tok*DMODEL + 2*i + 1] + cs;
  *(uint*)(hb + base + 2*i) = (uint)f2h(v0) | ((uint)f2h(v1) << 16);
}

// ---------------- 128x256 tiled f16 MFMA GEMM, ring-3, ONE barrier/K-tile -------
// r11 K-loop verbatim. Epilogue: 2 m-steps per barrier pair (r15 variant).
// EPI: 0 = bias->f16, 1 = bias+relu->f16

template<int K, int EPI>
__global__ __launch_bounds__(256, 2) void gemm_t(
    const ushort* __restrict__ A, const ushort* __restrict__ Bt,
    const float* __restrict__ bias, ushort* __restrict__ outb,
    const int ldc, const int nbn) {
  __shared__ __align__(16) char lds[73728];
  constexpr int NKT = K / 32;
  const int t = threadIdx.x;
  const int lane = t & 63, wc = t >> 6;
  const int cpx = (int)gridDim.x >> 3;
  const int wg  = ((int)blockIdx.x & 7) * cpx + ((int)blockIdx.x >> 3);
  const int bm = wg / nbn, bn = wg % nbn;

  const int fr = lane & 15;
  const int cxor = (((lane >> 4) ^ ((fr >> 1) & 3)) << 4);

  float bias_r[4];
  #pragma unroll
  for (int n = 0; n < 4; ++n) bias_r[n] = bias[bn*256 + wc*64 + n*16 + fr];
  asm volatile("" : "+v"(bias_r[0]), "+v"(bias_r[1]), "+v"(bias_r[2]), "+v"(bias_r[3]));

  const int srow = t >> 2;
  const int scc  = (t & 3) ^ ((t >> 3) & 3);
  const ushort* aSrc = A  + ((size_t)bm*128 + srow)*K + scc*8;
  const ushort* bSrc = Bt + ((size_t)bn*256 + srow)*K + scc*8;

  auto stage_t = [&](int j, int slot) {
    char* dst = lds + slot*24576 + t*16;
    const ushort* as = aSrc + j*32;
    load_lds16(as,                  dst);
    load_lds16(as + (size_t)64*K,   dst + 4096);
    const ushort* bs = bSrc + j*32;
    #pragma unroll
    for (int i = 0; i < 4; ++i)
      load_lds16(bs + (size_t)(i*64)*K, dst + 8192 + i*4096);
  };

  f32x4 acc[8][4] = {};

  stage_t(0, 0); stage_t(1, 1);
  asm volatile("s_waitcnt vmcnt(6)" ::: "memory");
  __builtin_amdgcn_s_barrier();

  int rs = 0, ss = 2;
  #pragma unroll 1
  for (int kt = 0; kt < NKT; ++kt) {
    const char* sl = lds + rs*24576;
    hfrag a[8], b[4];
    #pragma unroll
    for (int m = 0; m < 8; ++m)
      a[m] = *(const hfrag*)(sl + (m*16 + fr)*64 + cxor);
    #pragma unroll
    for (int n = 0; n < 4; ++n)
      b[n] = *(const hfrag*)(sl + 8192 + (wc*64 + n*16 + fr)*64 + cxor);
    if (kt + 2 < NKT) stage_t(kt + 2, ss);
    __builtin_amdgcn_s_setprio(1);
    #pragma unroll
    for (int m = 0; m < 8; ++m)
      #pragma unroll
      for (int n = 0; n < 4; ++n)
        acc[m][n] = mfma16(a[m], b[n], acc[m][n]);
    __builtin_amdgcn_s_setprio(0);
    if (kt + 2 < NKT) {
      asm volatile("s_waitcnt vmcnt(6)" ::: "memory");
    } else if (kt + 2 == NKT) {
      asm volatile("s_waitcnt vmcnt(0)" ::: "memory");
    }
    if (kt + 1 < NKT) __builtin_amdgcn_s_barrier();
    rs = (rs == 2) ? 0 : rs + 1;
    ss = (ss == 2) ? 0 : ss + 1;
  }

  // coalesced epilogue: 2 m-steps (32 rows, 16 KB) per barrier pair.
  #pragma unroll
  for (int mm = 0; mm < 4; ++mm) {
    __syncthreads();
    #pragma unroll
    for (int mi = 0; mi < 2; ++mi) {
      const int m = mm*2 + mi;
      #pragma unroll
      for (int n = 0; n < 4; ++n) {
        const int cc16 = wc*4 + n;
        #pragma unroll
        for (int r4 = 0; r4 < 4; ++r4) {
          const int rr = ((lane >> 4) << 2) + r4;            // 0..15
          float v = acc[m][n][r4] + bias_r[n];
          if constexpr (EPI == 1) v = fmaxf(v, 0.0f);
          *(ushort*)(lds + (mi*16 + rr)*512 + ((cc16 ^ (rr >> 2)) << 5) + fr*2) = f2h(v);
        }
      }
    }
    __syncthreads();
    #pragma unroll
    for (int pr = 0; pr < 2; ++pr) {
      const int lr = (t >> 4) + pr*16;                       // 0..31
      const int er16 = lr & 15;
      ushort* gp = outb + (size_t)(bm*128 + mm*32 + lr)*ldc + bn*256;
      #pragma unroll
      for (int pc = 0; pc < 2; ++pc) {
        const int cj = (t & 15) + pc*16;
        const uint4 v = *(const uint4*)(lds + lr*512 + (((cj >> 1) ^ (er16 >> 2)) << 5) + ((cj & 1) << 4));
        *(uint4*)(gp + cj*8) = v;
      }
    }
  }
}

// ---------------- fused attention + residual-LN1 ----------------
// Phase 3 two-pass via LDS: (a) v=h+delta accumulated AND written back into
// the delta slots (own addresses only), (b) after stats re-read + normalize.
// Removes the 64-VGPR vc[] cache (spill-proof).

__global__ __launch_bounds__(512, 1) void attn_ln(
    const ushort* __restrict__ qkv, ushort* __restrict__ hb) {
  __shared__ __align__(16) char lds[131072];
  __shared__ float red_[8], redq_[8], stat_[2];
  const int t = threadIdx.x;
  const int w = t >> 6, lane = t & 63;
  const int b = blockIdx.x, h = w;
  const int fr = lane & 15;
  const ushort* tokbase = qkv + (size_t)b*SEQ*1536;
  ushort* wl  = (ushort*)(lds + w*16384);
  ushort* kch = wl;
  ushort* vch = wl + 2048;

  f32x4 acc1[4][4] = {};
  #pragma unroll 1
  for (int sb = 0; sb < 4; ++sb) {
    const int s0 = sb*32;
    const int sr = lane >> 1;
    #pragma unroll
    for (int i = 0; i < 4; ++i) {
      const int cc  = i*2 + (lane & 1);
      const int ccs = cc ^ (sr & 7);
      const ushort* g = tokbase + (size_t)(s0+sr)*1536 + h*64 + cc*8;
      *(uint4*)(kch + sr*64 + ccs*8) = *(const uint4*)(g + 512);
      *(uint4*)(vch + sr*64 + ccs*8) = *(const uint4*)(g + 1024);
    }
    hfrag ak[4], av[4];
    #pragma unroll
    for (int m = 0; m < 4; ++m) {
      const int e1 = m*16 + (lane & 15);
      const int ccb = e1 >> 3, el = e1 & 7;
      #pragma unroll
      for (int j = 0; j < 8; ++j) {
        const int s = (lane >> 4)*8 + j;
        ak[m][j] = __builtin_bit_cast(_Float16, kch[s*64 + ((ccb ^ (s & 7))*8) + el]);
        av[m][j] = __builtin_bit_cast(_Float16, vch[s*64 + ((ccb ^ (s & 7))*8) + el]);
      }
    }
    #pragma unroll
    for (int m = 0; m < 4; ++m)
      #pragma unroll
      for (int n = 0; n < 4; ++n)
        acc1[m][n] = mfma16(ak[m], av[n], acc1[m][n]);
  }

  ushort* tv = wl;
  #pragma unroll
  for (int m = 0; m < 4; ++m)
    #pragma unroll
    for (int n = 0; n < 4; ++n)
      #pragma unroll
      for (int r4 = 0; r4 < 4; ++r4) {
        const int e1 = m*16 + (lane >> 4)*4 + r4;
        const int e2 = n*16 + (lane & 15);
        tv[e2*72 + e1] = f2h(acc1[m][n][r4] * 0.125f);
      }

  f32x4 acc2[8][4] = {};
  #pragma unroll
  for (int eb = 0; eb < 2; ++eb) {
    const int e1b = eb*32 + (lane >> 4)*8;
    hfrag aq[8], bk2[4];
    #pragma unroll
    for (int m = 0; m < 8; ++m) {
      const int s = m*16 + (lane & 15);
      aq[m] = *(const hfrag*)(tokbase + (size_t)s*1536 + h*64 + e1b);
    }
    #pragma unroll
    for (int n = 0; n < 4; ++n) {
      const int e2 = n*16 + (lane & 15);
      bk2[n] = *(const hfrag*)(tv + e2*72 + e1b);
    }
    #pragma unroll
    for (int m = 0; m < 8; ++m)
      #pragma unroll
      for (int n = 0; n < 4; ++n)
        acc2[m][n] = mfma16(aq[m], bk2[n], acc2[m][n]);
  }

  __syncthreads();
  #pragma unroll
  for (int m = 0; m < 8; ++m)
    #pragma unroll
    for (int n = 0; n < 4; ++n)
      #pragma unroll
      for (int r4 = 0; r4 < 4; ++r4) {
        const int row = m*16 + ((lane >> 4) << 2) + r4;
        const int ch  = (w*4 + n) ^ ((row >> 2) & 3) ^ (w >> 1);
        *(ushort*)(lds + row*1024 + ch*32 + fr*2) = f2h(acc2[m][n][r4]);
      }
  __syncthreads();

  // phase 3a: v = h + delta; accumulate; write v back into LDS (own slots)
  const int r = t >> 2, qd = t & 3;
  const ushort* hrow = hb + ((size_t)b*SEQ + r)*DMODEL + qd*128;
  float s = 0.f, q2 = 0.f;
  #pragma unroll
  for (int j = 0; j < 8; ++j) {
    const int ch = (qd*8 + j) ^ ((r >> 2) & 3) ^ qd;
    const uint4 d0 = *(const uint4*)(lds + r*1024 + ch*32);
    const uint4 d1 = *(const uint4*)(lds + r*1024 + ch*32 + 16);
    const uint4 h0 = *(const uint4*)(hrow + j*16);
    const uint4 h1 = *(const uint4*)(hrow + j*16 + 8);
    uint4 v0, v1;
    #pragma unroll
    for (int c = 0; c < 4; ++c) {
      float a0 = h2f((ushort)((&h0.x)[c] & 0xffffu)) + h2f((ushort)((&d0.x)[c] & 0xffffu));
      float a1 = h2f((ushort)((&h0.x)[c] >> 16))     + h2f((ushort)((&d0.x)[c] >> 16));
      float b0 = h2f((ushort)((&h1.x)[c] & 0xffffu)) + h2f((ushort)((&d1.x)[c] & 0xffffu));
      float b1 = h2f((ushort)((&h1.x)[c] >> 16))     + h2f((ushort)((&d1.x)[c] >> 16));
      s += a0 + a1 + b0 + b1;
      q2 += a0*a0 + a1*a1 + b0*b0 + b1*b1;
      (&v0.x)[c] = (uint)f2h(a0) | ((uint)f2h(a1) << 16);
      (&v1.x)[c] = (uint)f2h(b0) | ((uint)f2h(b1) << 16);
    }
    *(uint4*)(lds + r*1024 + ch*32)      = v0;
    *(uint4*)(lds + r*1024 + ch*32 + 16) = v1;
  }
  #pragma unroll
  for (int off = 32; off > 0; off >>= 1) {
    s  += __shfl_down(s, off);
    q2 += __shfl_down(q2, off);
  }
  if (lane == 0) { red_[w] = s; redq_[w] = q2; }
  __syncthreads();
  if (t == 0) {
    float S = 0.f, Q = 0.f;
    #pragma unroll
    for (int i = 0; i < 8; ++i) { S += red_[i]; Q += redq_[i]; }
    const float mean = S * (1.0f/65536.0f);
    stat_[0] = mean;
    stat_[1] = rsqrtf(Q * (1.0f/65536.0f) - mean*mean + 1e-5f);
  }
  __syncthreads();
  const float mean = stat_[0], rstd = stat_[1];
  // phase 3b: re-read v, normalize, store
  ushort* orow = hb + ((size_t)b*SEQ + r)*DMODEL + qd*128;
  #pragma unroll
  for (int j = 0; j < 8; ++j) {
    const int ch = (qd*8 + j) ^ ((r >> 2) & 3) ^ qd;
    #pragma unroll
    for (int half = 0; half < 2; ++half) {
      const uint4 u = *(const uint4*)(lds + r*1024 + ch*32 + half*16);
      uint4 o;
      #pragma unroll
      for (int c = 0; c < 4; ++c) {
        const float o0 = (h2f((ushort)((&u.x)[c] & 0xffffu)) - mean) * rstd;
        const float o1 = (h2f((ushort)((&u.x)[c] >> 16))     - mean) * rstd;
        (&o.x)[c] = (uint)f2h(o0) | ((uint)f2h(o1) << 16);
      }
      *(uint4*)(orow + j*16 + half*8) = o;
    }
  }
}

// ---------------- fused FF2 + residual-LN2 ----------------
// Phase 3 two-pass via LDS (no vc[] cache).

template<bool FINAL>
__global__ __launch_bounds__(512, 1) void gemm_f(
    const ushort* __restrict__ A, const ushort* __restrict__ Bt,
    const float* __restrict__ bias, ushort* __restrict__ hb, float* __restrict__ hf) {
  __shared__ __align__(16) char lds[131072];
  __shared__ float red_[8], redq_[8], stat_[2];
  constexpr int K = 2048, NKT = 64;
  const int t = threadIdx.x;
  const int lane = t & 63, w = t >> 6;
  const int bm = blockIdx.x;
  const int fr = lane & 15;
  const int cxor = (((lane >> 4) ^ ((fr >> 1) & 3)) << 4);

  float bias_r[4];
  #pragma unroll
  for (int n = 0; n < 4; ++n) bias_r[n] = bias[w*64 + n*16 + fr];
  asm volatile("" : "+v"(bias_r[0]), "+v"(bias_r[1]), "+v"(bias_r[2]), "+v"(bias_r[3]));

  const int srow = t >> 2;
  const int scc  = (t & 3) ^ ((t >> 3) & 3);
  const ushort* aSrc = A  + ((size_t)bm*128 + srow)*K + scc*8;
  const ushort* bSrc = Bt + (size_t)srow*K + scc*8;

  auto stage = [&](int j, int slot) {
    char* dst = lds + slot*40960 + t*16;
    load_lds16(aSrc + j*32, dst);
    #pragma unroll
    for (int i = 0; i < 4; ++i)
      load_lds16(bSrc + (size_t)(i*128)*K + j*32, dst + 8192 + i*8192);
  };

  f32x4 acc[8][4] = {};

  stage(0, 0); stage(1, 1);
  asm volatile("s_waitcnt vmcnt(5)" ::: "memory");
  __builtin_amdgcn_s_barrier();

  int rs = 0, ss = 2;
  #pragma unroll 1
  for (int kt = 0; kt < NKT; ++kt) {
    const char* sl = lds + rs*40960;
    hfrag a[8], b[4];
    #pragma unroll
    for (int m = 0; m < 8; ++m)
      a[m] = *(const hfrag*)(sl + (m*16 + fr)*64 + cxor);
    #pragma unroll
    for (int n = 0; n < 4; ++n)
      b[n] = *(const hfrag*)(sl + 8192 + (w*64 + n*16 + fr)*64 + cxor);
    if (kt + 2 < NKT) stage(kt + 2, ss);
    __builtin_amdgcn_s_setprio(1);
    #pragma unroll
    for (int m = 0; m < 8; ++m)
      #pragma unroll
      for (int n = 0; n < 4; ++n)
        acc[m][n] = mfma16(a[m], b[n], acc[m][n]);
    __builtin_amdgcn_s_setprio(0);
    if (kt + 2 < NKT) {
      asm volatile("s_waitcnt vmcnt(5)" ::: "memory");
    } else if (kt + 2 == NKT) {
      asm volatile("s_waitcnt vmcnt(0)" ::: "memory");
    }
    if (kt + 1 < NKT) __builtin_amdgcn_s_barrier();
    rs = (rs == 2) ? 0 : rs + 1;
    ss = (ss == 2) ? 0 : ss + 1;
  }

  __syncthreads();
  #pragma unroll
  for (int m = 0; m < 8; ++m)
    #pragma unroll
    for (int n = 0; n < 4; ++n)
      #pragma unroll
      for (int r4 = 0; r4 < 4; ++r4) {
        const int row = m*16 + ((lane >> 4) << 2) + r4;
        const int ch  = (w*4 + n) ^ ((row >> 2) & 3) ^ (w >> 1);
        *(ushort*)(lds + row*1024 + ch*32 + fr*2) = f2h(acc[m][n][r4] + bias_r[n]);
      }
  __syncthreads();

  // phase 3a: v = h + delta; accumulate; write v back into LDS (own slots)
  const int r = t >> 2, qd = t & 3;
  const ushort* hrow = hb + ((size_t)bm*SEQ + r)*DMODEL + qd*128;
  float s = 0.f, q2 = 0.f;
  #pragma unroll
  for (int j = 0; j < 8; ++j) {
    const int ch = (qd*8 + j) ^ ((r >> 2) & 3) ^ qd;
    const uint4 d0 = *(const uint4*)(lds + r*1024 + ch*32);
    const uint4 d1 = *(const uint4*)(lds + r*1024 + ch*32 + 16);
    const uint4 h0 = *(const uint4*)(hrow + j*16);
    const uint4 h1 = *(const uint4*)(hrow + j*16 + 8);
    uint4 v0, v1;
    #pragma unroll
    for (int c = 0; c < 4; ++c) {
      float a0 = h2f((ushort)((&h0.x)[c] & 0xffffu)) + h2f((ushort)((&d0.x)[c] & 0xffffu));
      float a1 = h2f((ushort)((&h0.x)[c] >> 16))     + h2f((ushort)((&d0.x)[c] >> 16));
      float b0 = h2f((ushort)((&h1.x)[c] & 0xffffu)) + h2f((ushort)((&d1.x)[c] & 0xffffu));
      float b1 = h2f((ushort)((&h1.x)[c] >> 16))     + h2f((ushort)((&d1.x)[c] >> 16));
      s += a0 + a1 + b0 + b1;
      q2 += a0*a0 + a1*a1 + b0*b0 + b1*b1;
      (&v0.x)[c] = (uint)f2h(a0) | ((uint)f2h(a1) << 16);
      (&v1.x)[c] = (uint)f2h(b0) | ((uint)f2h(b1) << 16);
    }
    *(uint4*)(lds + r*1024 + ch*32)      = v0;
    *(uint4*)(lds + r*1024 + ch*32 + 16) = v1;
  }
  #pragma unroll
  for (int off = 32; off > 0; off >>= 1) {
    s  += __shfl_down(s, off);
    q2 += __shfl_down(q2, off);
  }
  if (lane == 0) { red_[w] = s; redq_[w] = q2; }
  __syncthreads();
  if (t == 0) {
    float S = 0.f, Q = 0.f;
    #pragma unroll
    for (int i = 0; i < 8; ++i) { S += red_[i]; Q += redq_[i]; }
    const float mean = S * (1.0f/65536.0f);
    stat_[0] = mean;
    stat_[1] = rsqrtf(Q * (1.0f/65536.0f) - mean*mean + 1e-5f);
  }
  __syncthreads();
  const float mean = stat_[0], rstd = stat_[1];
  // phase 3b: re-read v, normalize, store
  if constexpr (FINAL) {
    float* frow = hf + ((size_t)bm*SEQ + r)*DMODEL + qd*128;
    #pragma unroll
    for (int j = 0; j < 8; ++j) {
      const int ch = (qd*8 + j) ^ ((r >> 2) & 3) ^ qd;
      #pragma unroll
      for (int half = 0; half < 2; ++half) {
        const uint4 u = *(const uint4*)(lds + r*1024 + ch*32 + half*16);
        f32x4 o0, o1;
        #pragma unroll
        for (int c = 0; c < 2; ++c) {
          o0[2*c]   = (h2f((ushort)((&u.x)[c] & 0xffffu)) - mean) * rstd;
          o0[2*c+1] = (h2f((ushort)((&u.x)[c] >> 16))     - mean) * rstd;
          o1[2*c]   = (h2f((ushort)((&u.x)[c+2] & 0xffffu)) - mean) * rstd;
          o1[2*c+1] = (h2f((ushort)((&u.x)[c+2] >> 16))     - mean) * rstd;
        }
        *(f32x4*)(frow + j*16 + half*8)     = o0;
        *(f32x4*)(frow + j*16 + half*8 + 4) = o1;
      }
    }
  } else {
    ushort* orow = hb + ((size_t)bm*SEQ + r)*DMODEL + qd*128;
    #pragma unroll
    for (int j = 0; j < 8; ++j) {
      const int ch = (qd*8 + j) ^ ((r >> 2) & 3) ^ qd;
      #pragma unroll
      for (int half = 0; half < 2; ++half) {
        const uint4 u = *(const uint4*)(lds + r*1024 + ch*32 + half*16);
        uint4 o;
        #pragma unroll
        for (int c = 0; c < 4; ++c) {
          const float o0 = (h2f((ushort)((&u.x)[c] & 0xffffu)) - mean) * rstd;
          const float o1 = (h2f((ushort)((&u.x)[c] >> 16))     - mean) * rstd;
          (&o.x)[c] = (uint)f2h(o0) | ((uint)f2h(o1) << 16);
        }
        *(uint4*)(orow + j*16 + half*8) = o;
      }
    }
  }
}

// ---------------- driver ----------------

extern "C" void kernel_launch(void* const* d_in, const int* in_sizes, int n_in,
                              void* d_out, int out_size, void* d_ws, size_t ws_size,
                              hipStream_t stream) {
  const int*   x   = (const int*)d_in[0];
  const float* emb = (const float*)d_in[1];
  const float* Wq  = (const float*)d_in[2];
  const float* bq  = (const float*)d_in[3];
  const float* Wk  = (const float*)d_in[4];
  const float* bk  = (const float*)d_in[5];
  const float* Wv  = (const float*)d_in[6];
  const float* bv  = (const float*)d_in[7];
  const float* W1  = (const float*)d_in[8];
  const float* b1  = (const float*)d_in[9];
  const float* W2  = (const float*)d_in[10];
  const float* b2  = (const float*)d_in[11];
  float* h = (float*)d_out;

  char* p = (char*)d_ws;
  size_t off = 0;
  auto alloc = [&](size_t bytes) { char* r = p + off; off += (bytes + 255) & ~(size_t)255; return r; };
  ushort* Wqkv_t = (ushort*)alloc((size_t)NLAYERS*1536*512*2);
  ushort* W1t    = (ushort*)alloc((size_t)NLAYERS*INNER*512*2);
  ushort* W2t    = (ushort*)alloc((size_t)NLAYERS*512*INNER*2);
  float*  biasq  = (float*)alloc((size_t)NLAYERS*1536*4);
  ushort* hbf    = (ushort*)alloc((size_t)NTOK*512*2);
  ushort* big    = (ushort*)alloc((size_t)NTOK*2048*2);  // qkv (1536) / FF inner (2048)

  prep_qkv<<<(NLAYERS*1536*512 + 255)/256, 256, 0, stream>>>(Wq, Wk, Wv, bq, bk, bv, Wqkv_t, biasq);
  prep_w1<<<(NLAYERS*INNER*512 + 255)/256, 256, 0, stream>>>(W1, W1t);
  prep_w2<<<(NLAYERS*512*INNER + 255)/256, 256, 0, stream>>>(W2, W2t);
  embed_kernel<<<NTOK, 256, 0, stream>>>(x, emb, hbf);

  for (int l = 0; l < NLAYERS; ++l) {
    // QKV: [32768,512] x [1536,512]^T -> dense [32768,1536] f16
    gemm_t<512,0><<<1536, 256, 0, stream>>>(
        hbf, Wqkv_t + (size_t)l*1536*512, biasq + (size_t)l*1536, big, 1536, 6);
    // attention + LN1 (fused): hb = LN(hb + attn)
    attn_ln<<<BATCH, 512, 0, stream>>>(big, hbf);
    // FF1: [32768,512] x [2048,512]^T -> relu -> big [32768,2048]
    gemm_t<512,1><<<2048, 256, 0, stream>>>(
        hbf, W1t + (size_t)l*INNER*512, b1 + (size_t)l*INNER, big, 2048, 8);
    // FF2 + LN2 (fused): hb = LN(hb + ff2); final layer writes f32 out
    if (l == NLAYERS-1) {
      gemm_f<true><<<BATCH, 512, 0, stream>>>(
          big, W2t + (size_t)l*512*INNER, b2 + (size_t)l*512, hbf, h);
    } else {
      gemm_f<false><<<BATCH, 512, 0, stream>>>(
          big, W2t + (size_t)l*512*INNER, b2 + (size_t)l*512, hbf, nullptr);
    }
  }
}